// Round 4
// baseline (111.000 us; speedup 1.0000x reference)
//
#include <hip/hip_runtime.h>
#include <math.h>

#define Bb   2
#define Hh   56
#define Ww   56
#define Cc   256
#define NHh  8
#define HDd  32
#define KK   7
#define HWsz (Hh*Ww)
#define Mtot (Bb*Hh*Ww)   // 6272

typedef __bf16 bf16x8 __attribute__((ext_vector_type(8)));
typedef __bf16 bf16x4 __attribute__((ext_vector_type(4)));
typedef float  f32x4  __attribute__((ext_vector_type(4)));

// One-shot fp32 -> bf16 conversion of x, w_qk, w_v, w_proj.
// Segments (in 8-element chunks): x 200704 | w_qk 16384 | w_v 8192 | w_proj 8192.
__global__ __launch_bounds__(256) void prep_bf16(
    const float* __restrict__ x, const float* __restrict__ wqk,
    const float* __restrict__ wv, const float* __restrict__ wp,
    __bf16* __restrict__ xb, __bf16* __restrict__ wallb, __bf16* __restrict__ wpb)
{
    const int t = blockIdx.x * 256 + threadIdx.x;   // 912*256 = 233472 chunks
    const float* src; __bf16* dst; int off;
    if (t < 200704)      { src = x;   dst = xb;             off = t; }
    else if (t < 217088) { src = wqk; dst = wallb;          off = t - 200704; }
    else if (t < 225280) { src = wv;  dst = wallb + 131072; off = t - 217088; }
    else                 { src = wp;  dst = wpb;            off = t - 225280; }
    const int e = off * 8;
    float4 a = *(const float4*)(src + e);
    float4 b = *(const float4*)(src + e + 4);
    bf16x8 o = { (__bf16)a.x, (__bf16)a.y, (__bf16)a.z, (__bf16)a.w,
                 (__bf16)b.x, (__bf16)b.y, (__bf16)b.z, (__bf16)b.w };
    *(bf16x8*)(dst + e) = o;
}

// QKV projection, full-K panel staging: A (M x 256 bf16) @ wallb^T (768 x 256).
// Entire 64x256 A and B panels staged to LDS once; single barrier; 32 MFMAs
// per wave with no intermediate syncs. LDS = 64 KB -> 2 blocks/CU.
// Per-(ks) block LDS layout + fragment reads identical to verified baseline.
__global__ __launch_bounds__(256) void gemm_qkv_p(
    const __bf16* __restrict__ A, const __bf16* __restrict__ Wall,
    __bf16* __restrict__ Out, float scale)
{
    __shared__ __bf16 As[16384];
    __shared__ __bf16 Bs[16384];

    const int tid = threadIdx.x;
    const int m0  = blockIdx.y * 64;
    const int n0  = blockIdx.x * 64;

    const int mm  = tid >> 2;        // 0..63: panel row
    const int q   = tid & 3;         // 0..3: 64-col slab
    const int sub = mm >> 4;
    const int row = mm & 15;
    const __bf16* arow = A    + (size_t)(m0 + mm) * 256 + q * 64;
    const __bf16* brow = Wall + (size_t)(n0 + mm) * 256 + q * 64;

    // stage full K=256 panels: 8 chunks of 8 bf16 per row-slab per thread
    #pragma unroll
    for (int i = 0; i < 8; ++i) {
        const int ks  = q * 2 + (i >> 2);          // absolute 32-col group 0..7
        const int c   = i & 3;                     // chunk within group
        const int off = (ks * 4 + sub) * 512 + row * 32 + ((c ^ (row & 3)) * 8);
        *(bf16x8*)&As[off] = *(const bf16x8*)(arow + i * 8);
        *(bf16x8*)&Bs[off] = *(const bf16x8*)(brow + i * 8);
    }
    __syncthreads();

    const int w    = tid >> 6;
    const int lane = tid & 63;
    const int fr_row = lane & 15;
    const int fr_c   = lane >> 4;
    const int fr_off = fr_row * 32 + ((fr_c ^ (fr_row & 3)) * 8);

    f32x4 acc[4] = {};
    #pragma unroll
    for (int ks = 0; ks < 8; ++ks) {
        bf16x8 af = *(const bf16x8*)&As[(ks * 4 + w) * 512 + fr_off];
        #pragma unroll
        for (int n = 0; n < 4; ++n) {
            bf16x8 bfr = *(const bf16x8*)&Bs[(ks * 4 + n) * 512 + fr_off];
            acc[n] = __builtin_amdgcn_mfma_f32_16x16x32_bf16(af, bfr, acc[n], 0, 0, 0);
        }
    }

    #pragma unroll
    for (int n = 0; n < 4; ++n) {
        const int gcol = n0 + n * 16 + fr_row;
        const float sc_ = (gcol < 256) ? scale : 1.f;
        #pragma unroll
        for (int r = 0; r < 4; ++r) {
            const int grow = m0 + w * 16 + fr_c * 4 + r;
            Out[(size_t)grow * 768 + gcol] = (__bf16)(acc[n][r] * sc_);
        }
    }
}

// Output projection, same full-K panel structure: attn_ws (M x 256 bf16)
// @ wpb^T (256 x 256 bf16); fp32 out + bias.
__global__ __launch_bounds__(256) void gemm_proj_p(
    const __bf16* __restrict__ A, const __bf16* __restrict__ W,
    float* __restrict__ Cout, const float* __restrict__ bias)
{
    __shared__ __bf16 As[16384];
    __shared__ __bf16 Bs[16384];

    const int N = 256;
    const int tid = threadIdx.x;
    const int m0  = blockIdx.y * 64;
    const int n0  = blockIdx.x * 64;

    const int mm  = tid >> 2;
    const int q   = tid & 3;
    const int sub = mm >> 4;
    const int row = mm & 15;
    const __bf16* arow = A + (size_t)(m0 + mm) * 256 + q * 64;
    const __bf16* brow = W + (size_t)(n0 + mm) * 256 + q * 64;

    #pragma unroll
    for (int i = 0; i < 8; ++i) {
        const int ks  = q * 2 + (i >> 2);
        const int c   = i & 3;
        const int off = (ks * 4 + sub) * 512 + row * 32 + ((c ^ (row & 3)) * 8);
        *(bf16x8*)&As[off] = *(const bf16x8*)(arow + i * 8);
        *(bf16x8*)&Bs[off] = *(const bf16x8*)(brow + i * 8);
    }
    __syncthreads();

    const int w    = tid >> 6;
    const int lane = tid & 63;
    const int fr_row = lane & 15;
    const int fr_c   = lane >> 4;
    const int fr_off = fr_row * 32 + ((fr_c ^ (fr_row & 3)) * 8);

    f32x4 acc[4] = {};
    #pragma unroll
    for (int ks = 0; ks < 8; ++ks) {
        bf16x8 af = *(const bf16x8*)&As[(ks * 4 + w) * 512 + fr_off];
        #pragma unroll
        for (int n = 0; n < 4; ++n) {
            bf16x8 bfr = *(const bf16x8*)&Bs[(ks * 4 + n) * 512 + fr_off];
            acc[n] = __builtin_amdgcn_mfma_f32_16x16x32_bf16(af, bfr, acc[n], 0, 0, 0);
        }
    }

    #pragma unroll
    for (int n = 0; n < 4; ++n) {
        const int gcol = n0 + n * 16 + fr_row;
        const float bs_ = bias[gcol];
        #pragma unroll
        for (int r = 0; r < 4; ++r) {
            const int grow = m0 + w * 16 + fr_c * 4 + r;
            Cout[(size_t)grow * N + gcol] = acc[n][r] + bs_;
        }
    }
}

// Neighborhood attention, 8x4 query tile per (b, head). 256 threads.
// qkv: bf16 rows of 768 (q | k | v). Q -> fp32 regs; K/V bf16 LDS;
// probs fp32 LDS; fp32 accum. LDS = 140*40*2 + 32*49*4 = 17.2 KB.
__global__ __launch_bounds__(256, 5) void nattn_84(
    const __bf16* __restrict__ qkv, __bf16* __restrict__ attn_out,
    float* __restrict__ attn_glob)
{
    __shared__ __align__(16) __bf16 Ks[140 * 40];   // K then V (bf16)
    __shared__ float Ss[32 * 49];                   // probs

    const int bx   = blockIdx.x;
    const int head = bx & 7;
    int t = bx >> 3;
    const int tj = t % 14; t /= 14;
    const int ti = t % 7;
    const int b  = t / 7;
    const int tid = threadIdx.x;

    int base_h = ti * 8 - 3; if (base_h < 0) base_h = 0; if (base_h > Hh - 14) base_h = Hh - 14;
    int base_w = tj * 4 - 3; if (base_w < 0) base_w = 0; if (base_w > Ww - 10) base_w = Ww - 10;

    const int pixb = b * HWsz;
    const int hoff = head * 32;

    // --- stage K into LDS: 140 rows x 4 chunks of 8 dims ---
    #pragma unroll
    for (int it = 0; it < 3; ++it) {
        const int idx = tid + it * 256;
        if (idx < 560) {
            const int p = idx >> 2, c = idx & 3;
            const int pix = pixb + (base_h + p / 10) * Ww + base_w + p % 10;
            *(bf16x8*)&Ks[p * 40 + c * 8] =
                *(const bf16x8*)&qkv[(size_t)pix * 768 + 256 + hoff + c * 8];
        }
    }

    const int q  = tid >> 3;
    const int r  = tid & 7;
    const int qi = ti * 8 + (q >> 2);
    const int qj = tj * 4 + (q & 3);

    float qreg[32];
    {
        const __bf16* qp = &qkv[(size_t)(pixb + qi * Ww + qj) * 768 + hoff];
        #pragma unroll
        for (int c = 0; c < 4; ++c) {
            bf16x8 qv = *(const bf16x8*)(qp + c * 8);
            #pragma unroll
            for (int j = 0; j < 8; ++j) qreg[c * 8 + j] = (float)qv[j];
        }
    }

    // --- prefetch V to registers ---
    bf16x8 vreg[3];
    #pragma unroll
    for (int it = 0; it < 3; ++it) {
        const int idx = tid + it * 256;
        if (idx < 560) {
            const int p = idx >> 2, c = idx & 3;
            const int pix = pixb + (base_h + p / 10) * Ww + base_w + p % 10;
            vreg[it] = *(const bf16x8*)&qkv[(size_t)pix * 768 + 512 + hoff + c * 8];
        }
    }
    __syncthreads();

    int ih0 = qi - 3; if (ih0 < 0) ih0 = 0; if (ih0 > Hh - 7) ih0 = Hh - 7;
    int iw0 = qj - 3; if (iw0 < 0) iw0 = 0; if (iw0 > Ww - 7) iw0 = Ww - 7;
    const int lh0 = ih0 - base_h, lw0 = iw0 - base_w;

    // --- QK ---
    float sc[7];
    float mx = -1e30f;
    #pragma unroll
    for (int tt = 0; tt < 7; ++tt) {
        const int k = r + 8 * tt;
        if (k < 49) {
            const int krow = (lh0 + k / 7) * 10 + lw0 + k % 7;
            const __bf16* kp = &Ks[krow * 40];
            float acc = 0.f;
            #pragma unroll
            for (int c = 0; c < 4; ++c) {
                bf16x8 kv = *(const bf16x8*)(kp + c * 8);
                #pragma unroll
                for (int j = 0; j < 8; ++j)
                    acc += qreg[c * 8 + j] * (float)kv[j];
            }
            sc[tt] = acc;
            mx = fmaxf(mx, acc);
        }
    }
    mx = fmaxf(mx, __shfl_xor(mx, 1));
    mx = fmaxf(mx, __shfl_xor(mx, 2));
    mx = fmaxf(mx, __shfl_xor(mx, 4));
    float sum = 0.f;
    #pragma unroll
    for (int tt = 0; tt < 7; ++tt) {
        const int k = r + 8 * tt;
        if (k < 49) { sc[tt] = __expf(sc[tt] - mx); sum += sc[tt]; }
    }
    sum += __shfl_xor(sum, 1);
    sum += __shfl_xor(sum, 2);
    sum += __shfl_xor(sum, 4);
    const float inv = 1.f / sum;
    #pragma unroll
    for (int tt = 0; tt < 7; ++tt) {
        const int k = r + 8 * tt;
        if (k < 49) Ss[q * 49 + k] = sc[tt] * inv;
    }
    __syncthreads();

    // --- V regs -> LDS; attn probs -> global ---
    #pragma unroll
    for (int it = 0; it < 3; ++it) {
        const int idx = tid + it * 256;
        if (idx < 560) {
            const int p = idx >> 2, c = idx & 3;
            *(bf16x8*)&Ks[p * 40 + c * 8] = vreg[it];
        }
    }
    const size_t agbase = (size_t)(b * NHh + head) * HWsz;
    for (int idx = tid; idx < 32 * 49; idx += 256) {
        const int qq = idx / 49, k = idx - qq * 49;
        attn_glob[(agbase + (ti * 8 + (qq >> 2)) * Ww + tj * 4 + (qq & 3)) * 49 + k]
            = Ss[qq * 49 + k];
    }
    __syncthreads();

    // --- PV: dim chunk rc = r&3 (8 dims), key parity par = r>>2 ---
    const int rc  = r & 3;
    const int par = r >> 2;
    float a[8] = {};
    #pragma unroll
    for (int tt = 0; tt < 25; ++tt) {
        const int k = par + 2 * tt;
        if (k < 49) {
            const float pr = Ss[q * 49 + k];
            const int vrow = (lh0 + k / 7) * 10 + lw0 + k % 7;
            bf16x8 v8 = *(const bf16x8*)&Ks[vrow * 40 + rc * 8];
            #pragma unroll
            for (int j = 0; j < 8; ++j)
                a[j] += pr * (float)v8[j];
        }
    }
    #pragma unroll
    for (int j = 0; j < 8; ++j) a[j] += __shfl_xor(a[j], 4);

    bf16x4 o = { (__bf16)a[par * 4 + 0], (__bf16)a[par * 4 + 1],
                 (__bf16)a[par * 4 + 2], (__bf16)a[par * 4 + 3] };
    *(bf16x4*)(attn_out + (size_t)(pixb + qi * Ww + qj) * 256 + hoff + rc * 8 + par * 4) = o;
}

extern "C" void kernel_launch(void* const* d_in, const int* in_sizes, int n_in,
                              void* d_out, int out_size, void* d_ws, size_t ws_size,
                              hipStream_t stream)
{
    const float* x      = (const float*)d_in[0];
    const float* w_qk   = (const float*)d_in[1];
    const float* w_v    = (const float*)d_in[2];
    const float* w_proj = (const float*)d_in[3];
    const float* b_proj = (const float*)d_in[4];

    float* out       = (float*)d_out;                    // chunk 0: (B,H,W,C)
    float* attn_glob = out + (size_t)Mtot * Cc;          // chunk 1: (B,NH,H,W,49)

    __bf16* xb      = (__bf16*)d_ws;                     // M x 256
    __bf16* wallb   = xb + (size_t)Mtot * 256;           // 768 x 256 (qk | v)
    __bf16* wpb     = wallb + 768 * 256;                 // 256 x 256
    __bf16* qkv_ws  = wpb + 256 * 256;                   // M x 768 (q|k|v)
    __bf16* attn_ws = qkv_ws + (size_t)Mtot * 768;       // M x 256

    const float scale = 0.17677669529663687f;            // HD^-0.5

    prep_bf16<<<912, 256, 0, stream>>>(x, w_qk, w_v, w_proj, xb, wallb, wpb);

    gemm_qkv_p<<<dim3(768 / 64, Mtot / 64), 256, 0, stream>>>(
        xb, wallb, qkv_ws, scale);

    nattn_84<<<Bb * 7 * 14 * NHh, 256, 0, stream>>>(qkv_ws, attn_ws, attn_glob);

    gemm_proj_p<<<dim3(256 / 64, Mtot / 64), 256, 0, stream>>>(
        attn_ws, wpb, out, b_proj);
}

// Round 6
// 106.160 us; speedup vs baseline: 1.0456x; 1.0456x over previous
//
#include <hip/hip_runtime.h>
#include <math.h>

#define Bb   2
#define Hh   56
#define Ww   56
#define Cc   256
#define NHh  8
#define HDd  32
#define KK   7
#define HWsz (Hh*Ww)
#define Mtot (Bb*Hh*Ww)   // 6272

typedef __bf16 bf16x8 __attribute__((ext_vector_type(8)));
typedef __bf16 bf16x4 __attribute__((ext_vector_type(4)));
typedef float  f32x4  __attribute__((ext_vector_type(4)));

// One-shot fp32 -> bf16 conversion of x, w_qk, w_v, w_proj.
// Segments (in 8-element chunks): x 200704 | w_qk 16384 | w_v 8192 | w_proj 8192.
__global__ __launch_bounds__(256) void prep_bf16(
    const float* __restrict__ x, const float* __restrict__ wqk,
    const float* __restrict__ wv, const float* __restrict__ wp,
    __bf16* __restrict__ xb, __bf16* __restrict__ wallb, __bf16* __restrict__ wpb)
{
    const int t = blockIdx.x * 256 + threadIdx.x;   // 912*256 = 233472 chunks
    const float* src; __bf16* dst; int off;
    if (t < 200704)      { src = x;   dst = xb;             off = t; }
    else if (t < 217088) { src = wqk; dst = wallb;          off = t - 200704; }
    else if (t < 225280) { src = wv;  dst = wallb + 131072; off = t - 217088; }
    else                 { src = wp;  dst = wpb;            off = t - 225280; }
    const int e = off * 8;
    float4 a = *(const float4*)(src + e);
    float4 b = *(const float4*)(src + e + 4);
    bf16x8 o = { (__bf16)a.x, (__bf16)a.y, (__bf16)a.z, (__bf16)a.w,
                 (__bf16)b.x, (__bf16)b.y, (__bf16)b.z, (__bf16)b.w };
    *(bf16x8*)(dst + e) = o;
}

// QKV projection, pure bf16: A (M x 256 bf16) @ wallb^T (768 x 256 bf16).
// Out: qkv bf16 rows of 768 (q scaled | k | v). 64x64 tile, BK=64, 4 waves.
// 1D grid (1176 = 8*147) with XCD-chunked swizzle: each XCD gets 147
// consecutive logical tiles (n fastest) -> A-panel reuse is L2-local.
__global__ __launch_bounds__(256) void gemm_qkv_b(
    const __bf16* __restrict__ A, const __bf16* __restrict__ Wall,
    __bf16* __restrict__ Out, float scale)
{
    __shared__ __bf16 As[4096];
    __shared__ __bf16 Bs[4096];

    const int Kdim = 256;
    const int tid = threadIdx.x;
    const int bid = blockIdx.x;
    const int swz = (bid & 7) * 147 + (bid >> 3);   // bijective, 1176 blocks
    const int m0  = (swz / 12) * 64;
    const int n0  = (swz % 12) * 64;

    const int mm = tid >> 2;
    const int q  = tid & 3;
    const __bf16* arow = A    + (size_t)(m0 + mm) * Kdim + q * 16;
    const __bf16* brow = Wall + (size_t)(n0 + mm) * Kdim + q * 16;

    const int ks_st  = q >> 1;
    const int sub_st = mm >> 4;
    const int row_st = mm & 15;
    const int c0_st  = (q & 1) * 2;
    const int blk_st = ks_st * 4 + sub_st;
    const int off0 = blk_st * 512 + row_st * 32 + ((c0_st ^ (row_st & 3)) * 8);
    const int off1 = blk_st * 512 + row_st * 32 + (((c0_st + 1) ^ (row_st & 3)) * 8);

    const int w    = tid >> 6;
    const int lane = tid & 63;
    const int fr_row = lane & 15;
    const int fr_c   = lane >> 4;
    const int fr_off = fr_row * 32 + ((fr_c ^ (fr_row & 3)) * 8);

    f32x4 acc[4] = {};

    for (int k0 = 0; k0 < Kdim; k0 += 64) {
        bf16x8 av0 = *(const bf16x8*)(arow + k0);
        bf16x8 av1 = *(const bf16x8*)(arow + k0 + 8);
        bf16x8 bv0 = *(const bf16x8*)(brow + k0);
        bf16x8 bv1 = *(const bf16x8*)(brow + k0 + 8);
        __syncthreads();
        *(bf16x8*)&As[off0] = av0;
        *(bf16x8*)&As[off1] = av1;
        *(bf16x8*)&Bs[off0] = bv0;
        *(bf16x8*)&Bs[off1] = bv1;
        __syncthreads();
        #pragma unroll
        for (int ks = 0; ks < 2; ++ks) {
            bf16x8 af = *(const bf16x8*)&As[(ks * 4 + w) * 512 + fr_off];
            #pragma unroll
            for (int n = 0; n < 4; ++n) {
                bf16x8 bfr = *(const bf16x8*)&Bs[(ks * 4 + n) * 512 + fr_off];
                acc[n] = __builtin_amdgcn_mfma_f32_16x16x32_bf16(af, bfr, acc[n], 0, 0, 0);
            }
        }
    }

    #pragma unroll
    for (int n = 0; n < 4; ++n) {
        const int gcol = n0 + n * 16 + fr_row;
        const float sc_ = (gcol < 256) ? scale : 1.f;
        #pragma unroll
        for (int r = 0; r < 4; ++r) {
            const int grow = m0 + w * 16 + fr_c * 4 + r;
            Out[(size_t)grow * 768 + gcol] = (__bf16)(acc[n][r] * sc_);
        }
    }
}

// Output projection, bf16 operands: attn (M x 256 bf16) @ wpb^T; fp32 out + bias.
// 1D grid (392 = 8*49) with XCD-chunked swizzle.
__global__ __launch_bounds__(256) void gemm_proj_b(
    const __bf16* __restrict__ A, const __bf16* __restrict__ W,
    float* __restrict__ Cout, const float* __restrict__ bias)
{
    __shared__ __bf16 As[4096];
    __shared__ __bf16 Bs[4096];

    const int Kdim = 256, N = 256;
    const int tid = threadIdx.x;
    const int bid = blockIdx.x;
    const int swz = (bid & 7) * 49 + (bid >> 3);    // bijective, 392 blocks
    const int m0  = (swz / 4) * 64;
    const int n0  = (swz % 4) * 64;

    const int mm = tid >> 2;
    const int q  = tid & 3;
    const __bf16* arow = A + (size_t)(m0 + mm) * Kdim + q * 16;
    const __bf16* brow = W + (size_t)(n0 + mm) * Kdim + q * 16;

    const int ks_st  = q >> 1;
    const int sub_st = mm >> 4;
    const int row_st = mm & 15;
    const int c0_st  = (q & 1) * 2;
    const int blk_st = ks_st * 4 + sub_st;
    const int off0 = blk_st * 512 + row_st * 32 + ((c0_st ^ (row_st & 3)) * 8);
    const int off1 = blk_st * 512 + row_st * 32 + (((c0_st + 1) ^ (row_st & 3)) * 8);

    const int w    = tid >> 6;
    const int lane = tid & 63;
    const int fr_row = lane & 15;
    const int fr_c   = lane >> 4;
    const int fr_off = fr_row * 32 + ((fr_c ^ (fr_row & 3)) * 8);

    f32x4 acc[4] = {};

    for (int k0 = 0; k0 < Kdim; k0 += 64) {
        bf16x8 av0 = *(const bf16x8*)(arow + k0);
        bf16x8 av1 = *(const bf16x8*)(arow + k0 + 8);
        bf16x8 bv0 = *(const bf16x8*)(brow + k0);
        bf16x8 bv1 = *(const bf16x8*)(brow + k0 + 8);
        __syncthreads();
        *(bf16x8*)&As[off0] = av0;
        *(bf16x8*)&As[off1] = av1;
        *(bf16x8*)&Bs[off0] = bv0;
        *(bf16x8*)&Bs[off1] = bv1;
        __syncthreads();
        #pragma unroll
        for (int ks = 0; ks < 2; ++ks) {
            bf16x8 af = *(const bf16x8*)&As[(ks * 4 + w) * 512 + fr_off];
            #pragma unroll
            for (int n = 0; n < 4; ++n) {
                bf16x8 bfr = *(const bf16x8*)&Bs[(ks * 4 + n) * 512 + fr_off];
                acc[n] = __builtin_amdgcn_mfma_f32_16x16x32_bf16(af, bfr, acc[n], 0, 0, 0);
            }
        }
    }

    #pragma unroll
    for (int n = 0; n < 4; ++n) {
        const int gcol = n0 + n * 16 + fr_row;
        const float bs_ = bias[gcol];
        #pragma unroll
        for (int r = 0; r < 4; ++r) {
            const int grow = m0 + w * 16 + fr_c * 4 + r;
            Cout[(size_t)grow * N + gcol] = acc[n][r] + bs_;
        }
    }
}

// Neighborhood attention, 8x4 query tile per (b, head). 256 threads.
// XCD-chunked swizzle (1568 = 8*196): the 8 heads of a tile (consecutive
// logical ids, sharing the same 140 K/V pixel rows) land on one XCD.
__global__ __launch_bounds__(256, 5) void nattn_84(
    const __bf16* __restrict__ qkv, __bf16* __restrict__ attn_out,
    float* __restrict__ attn_glob)
{
    __shared__ __align__(16) __bf16 Ks[140 * 40];   // K then V (bf16)
    __shared__ float Ss[32 * 49];                   // probs

    const int bid = blockIdx.x;
    const int swz = (bid & 7) * 196 + (bid >> 3);   // bijective, 1568 blocks
    const int head = swz & 7;
    int t = swz >> 3;
    const int tj = t % 14; t /= 14;
    const int ti = t % 7;
    const int b  = t / 7;
    const int tid = threadIdx.x;

    int base_h = ti * 8 - 3; if (base_h < 0) base_h = 0; if (base_h > Hh - 14) base_h = Hh - 14;
    int base_w = tj * 4 - 3; if (base_w < 0) base_w = 0; if (base_w > Ww - 10) base_w = Ww - 10;

    const int pixb = b * HWsz;
    const int hoff = head * 32;

    // --- stage K into LDS: 140 rows x 4 chunks of 8 dims ---
    #pragma unroll
    for (int it = 0; it < 3; ++it) {
        const int idx = tid + it * 256;
        if (idx < 560) {
            const int p = idx >> 2, c = idx & 3;
            const int pix = pixb + (base_h + p / 10) * Ww + base_w + p % 10;
            *(bf16x8*)&Ks[p * 40 + c * 8] =
                *(const bf16x8*)&qkv[(size_t)pix * 768 + 256 + hoff + c * 8];
        }
    }

    const int q  = tid >> 3;
    const int r  = tid & 7;
    const int qi = ti * 8 + (q >> 2);
    const int qj = tj * 4 + (q & 3);

    float qreg[32];
    {
        const __bf16* qp = &qkv[(size_t)(pixb + qi * Ww + qj) * 768 + hoff];
        #pragma unroll
        for (int c = 0; c < 4; ++c) {
            bf16x8 qv = *(const bf16x8*)(qp + c * 8);
            #pragma unroll
            for (int j = 0; j < 8; ++j) qreg[c * 8 + j] = (float)qv[j];
        }
    }

    // --- prefetch V to registers ---
    bf16x8 vreg[3];
    #pragma unroll
    for (int it = 0; it < 3; ++it) {
        const int idx = tid + it * 256;
        if (idx < 560) {
            const int p = idx >> 2, c = idx & 3;
            const int pix = pixb + (base_h + p / 10) * Ww + base_w + p % 10;
            vreg[it] = *(const bf16x8*)&qkv[(size_t)pix * 768 + 512 + hoff + c * 8];
        }
    }
    __syncthreads();

    int ih0 = qi - 3; if (ih0 < 0) ih0 = 0; if (ih0 > Hh - 7) ih0 = Hh - 7;
    int iw0 = qj - 3; if (iw0 < 0) iw0 = 0; if (iw0 > Ww - 7) iw0 = Ww - 7;
    const int lh0 = ih0 - base_h, lw0 = iw0 - base_w;

    // --- QK ---
    float sc[7];
    float mx = -1e30f;
    #pragma unroll
    for (int tt = 0; tt < 7; ++tt) {
        const int k = r + 8 * tt;
        if (k < 49) {
            const int krow = (lh0 + k / 7) * 10 + lw0 + k % 7;
            const __bf16* kp = &Ks[krow * 40];
            float acc = 0.f;
            #pragma unroll
            for (int c = 0; c < 4; ++c) {
                bf16x8 kv = *(const bf16x8*)(kp + c * 8);
                #pragma unroll
                for (int j = 0; j < 8; ++j)
                    acc += qreg[c * 8 + j] * (float)kv[j];
            }
            sc[tt] = acc;
            mx = fmaxf(mx, acc);
        }
    }
    mx = fmaxf(mx, __shfl_xor(mx, 1));
    mx = fmaxf(mx, __shfl_xor(mx, 2));
    mx = fmaxf(mx, __shfl_xor(mx, 4));
    float sum = 0.f;
    #pragma unroll
    for (int tt = 0; tt < 7; ++tt) {
        const int k = r + 8 * tt;
        if (k < 49) { sc[tt] = __expf(sc[tt] - mx); sum += sc[tt]; }
    }
    sum += __shfl_xor(sum, 1);
    sum += __shfl_xor(sum, 2);
    sum += __shfl_xor(sum, 4);
    const float inv = 1.f / sum;
    #pragma unroll
    for (int tt = 0; tt < 7; ++tt) {
        const int k = r + 8 * tt;
        if (k < 49) Ss[q * 49 + k] = sc[tt] * inv;
    }
    __syncthreads();

    // --- V regs -> LDS; attn probs -> global ---
    #pragma unroll
    for (int it = 0; it < 3; ++it) {
        const int idx = tid + it * 256;
        if (idx < 560) {
            const int p = idx >> 2, c = idx & 3;
            *(bf16x8*)&Ks[p * 40 + c * 8] = vreg[it];
        }
    }
    const size_t agbase = (size_t)(b * NHh + head) * HWsz;
    for (int idx = tid; idx < 32 * 49; idx += 256) {
        const int qq = idx / 49, k = idx - qq * 49;
        attn_glob[(agbase + (ti * 8 + (qq >> 2)) * Ww + tj * 4 + (qq & 3)) * 49 + k]
            = Ss[qq * 49 + k];
    }
    __syncthreads();

    // --- PV: dim chunk rc = r&3 (8 dims), key parity par = r>>2 ---
    const int rc  = r & 3;
    const int par = r >> 2;
    float a[8] = {};
    #pragma unroll
    for (int tt = 0; tt < 25; ++tt) {
        const int k = par + 2 * tt;
        if (k < 49) {
            const float pr = Ss[q * 49 + k];
            const int vrow = (lh0 + k / 7) * 10 + lw0 + k % 7;
            bf16x8 v8 = *(const bf16x8*)&Ks[vrow * 40 + rc * 8];
            #pragma unroll
            for (int j = 0; j < 8; ++j)
                a[j] += pr * (float)v8[j];
        }
    }
    #pragma unroll
    for (int j = 0; j < 8; ++j) a[j] += __shfl_xor(a[j], 4);

    bf16x4 o = { (__bf16)a[par * 4 + 0], (__bf16)a[par * 4 + 1],
                 (__bf16)a[par * 4 + 2], (__bf16)a[par * 4 + 3] };
    *(bf16x4*)(attn_out + (size_t)(pixb + qi * Ww + qj) * 256 + hoff + rc * 8 + par * 4) = o;
}

extern "C" void kernel_launch(void* const* d_in, const int* in_sizes, int n_in,
                              void* d_out, int out_size, void* d_ws, size_t ws_size,
                              hipStream_t stream)
{
    const float* x      = (const float*)d_in[0];
    const float* w_qk   = (const float*)d_in[1];
    const float* w_v    = (const float*)d_in[2];
    const float* w_proj = (const float*)d_in[3];
    const float* b_proj = (const float*)d_in[4];

    float* out       = (float*)d_out;                    // chunk 0: (B,H,W,C)
    float* attn_glob = out + (size_t)Mtot * Cc;          // chunk 1: (B,NH,H,W,49)

    __bf16* xb      = (__bf16*)d_ws;                     // M x 256
    __bf16* wallb   = xb + (size_t)Mtot * 256;           // 768 x 256 (qk | v)
    __bf16* wpb     = wallb + 768 * 256;                 // 256 x 256
    __bf16* qkv_ws  = wpb + 256 * 256;                   // M x 768 (q|k|v)
    __bf16* attn_ws = qkv_ws + (size_t)Mtot * 768;       // M x 256

    const float scale = 0.17677669529663687f;            // HD^-0.5

    prep_bf16<<<912, 256, 0, stream>>>(x, w_qk, w_v, w_proj, xb, wallb, wpb);

    gemm_qkv_b<<<1176, 256, 0, stream>>>(xb, wallb, qkv_ws, scale);

    nattn_84<<<Bb * 7 * 14 * NHh, 256, 0, stream>>>(qkv_ws, attn_ws, attn_glob);

    gemm_proj_b<<<392, 256, 0, stream>>>(attn_ws, wpb, out, b_proj);
}

// Round 11
// 105.599 us; speedup vs baseline: 1.0511x; 1.0053x over previous
//
#include <hip/hip_runtime.h>
#include <math.h>

#define Bb   2
#define Hh   56
#define Ww   56
#define Cc   256
#define NHh  8
#define HDd  32
#define KK   7
#define HWsz (Hh*Ww)
#define Mtot (Bb*Hh*Ww)   // 6272

typedef __bf16 bf16x8 __attribute__((ext_vector_type(8)));
typedef __bf16 bf16x4 __attribute__((ext_vector_type(4)));
typedef float  f32x4  __attribute__((ext_vector_type(4)));

// One-shot fp32 -> bf16 conversion of x, w_qk, w_v, w_proj.
__global__ __launch_bounds__(256) void prep_bf16(
    const float* __restrict__ x, const float* __restrict__ wqk,
    const float* __restrict__ wv, const float* __restrict__ wp,
    __bf16* __restrict__ xb, __bf16* __restrict__ wallb, __bf16* __restrict__ wpb)
{
    const int t = blockIdx.x * 256 + threadIdx.x;   // 912*256 = 233472 chunks
    const float* src; __bf16* dst; int off;
    if (t < 200704)      { src = x;   dst = xb;             off = t; }
    else if (t < 217088) { src = wqk; dst = wallb;          off = t - 200704; }
    else if (t < 225280) { src = wv;  dst = wallb + 131072; off = t - 217088; }
    else                 { src = wp;  dst = wpb;            off = t - 225280; }
    const int e = off * 8;
    float4 a = *(const float4*)(src + e);
    float4 b = *(const float4*)(src + e + 4);
    bf16x8 o = { (__bf16)a.x, (__bf16)a.y, (__bf16)a.z, (__bf16)a.w,
                 (__bf16)b.x, (__bf16)b.y, (__bf16)b.z, (__bf16)b.w };
    *(bf16x8*)(dst + e) = o;
}

// QKV projection, pure bf16: A (M x 256 bf16) @ wallb^T (768 x 256 bf16).
// 1D grid (1176 = 8*147) with XCD-chunked swizzle.
__global__ __launch_bounds__(256) void gemm_qkv_b(
    const __bf16* __restrict__ A, const __bf16* __restrict__ Wall,
    __bf16* __restrict__ Out, float scale)
{
    __shared__ __bf16 As[4096];
    __shared__ __bf16 Bs[4096];

    const int Kdim = 256;
    const int tid = threadIdx.x;
    const int bid = blockIdx.x;
    const int swz = (bid & 7) * 147 + (bid >> 3);   // bijective, 1176 blocks
    const int m0  = (swz / 12) * 64;
    const int n0  = (swz % 12) * 64;

    const int mm = tid >> 2;
    const int q  = tid & 3;
    const __bf16* arow = A    + (size_t)(m0 + mm) * Kdim + q * 16;
    const __bf16* brow = Wall + (size_t)(n0 + mm) * Kdim + q * 16;

    const int ks_st  = q >> 1;
    const int sub_st = mm >> 4;
    const int row_st = mm & 15;
    const int c0_st  = (q & 1) * 2;
    const int blk_st = ks_st * 4 + sub_st;
    const int off0 = blk_st * 512 + row_st * 32 + ((c0_st ^ (row_st & 3)) * 8);
    const int off1 = blk_st * 512 + row_st * 32 + (((c0_st + 1) ^ (row_st & 3)) * 8);

    const int w    = tid >> 6;
    const int lane = tid & 63;
    const int fr_row = lane & 15;
    const int fr_c   = lane >> 4;
    const int fr_off = fr_row * 32 + ((fr_c ^ (fr_row & 3)) * 8);

    f32x4 acc[4] = {};

    for (int k0 = 0; k0 < Kdim; k0 += 64) {
        bf16x8 av0 = *(const bf16x8*)(arow + k0);
        bf16x8 av1 = *(const bf16x8*)(arow + k0 + 8);
        bf16x8 bv0 = *(const bf16x8*)(brow + k0);
        bf16x8 bv1 = *(const bf16x8*)(brow + k0 + 8);
        __syncthreads();
        *(bf16x8*)&As[off0] = av0;
        *(bf16x8*)&As[off1] = av1;
        *(bf16x8*)&Bs[off0] = bv0;
        *(bf16x8*)&Bs[off1] = bv1;
        __syncthreads();
        #pragma unroll
        for (int ks = 0; ks < 2; ++ks) {
            bf16x8 af = *(const bf16x8*)&As[(ks * 4 + w) * 512 + fr_off];
            #pragma unroll
            for (int n = 0; n < 4; ++n) {
                bf16x8 bfr = *(const bf16x8*)&Bs[(ks * 4 + n) * 512 + fr_off];
                acc[n] = __builtin_amdgcn_mfma_f32_16x16x32_bf16(af, bfr, acc[n], 0, 0, 0);
            }
        }
    }

    #pragma unroll
    for (int n = 0; n < 4; ++n) {
        const int gcol = n0 + n * 16 + fr_row;
        const float sc_ = (gcol < 256) ? scale : 1.f;
        #pragma unroll
        for (int r = 0; r < 4; ++r) {
            const int grow = m0 + w * 16 + fr_c * 4 + r;
            Out[(size_t)grow * 768 + gcol] = (__bf16)(acc[n][r] * sc_);
        }
    }
}

// Output projection, bf16 operands: attn (M x 256 bf16) @ wpb^T; fp32 out + bias.
// 1D grid (392 = 8*49) with XCD-chunked swizzle.
__global__ __launch_bounds__(256) void gemm_proj_b(
    const __bf16* __restrict__ A, const __bf16* __restrict__ W,
    float* __restrict__ Cout, const float* __restrict__ bias)
{
    __shared__ __bf16 As[4096];
    __shared__ __bf16 Bs[4096];

    const int Kdim = 256, N = 256;
    const int tid = threadIdx.x;
    const int bid = blockIdx.x;
    const int swz = (bid & 7) * 49 + (bid >> 3);    // bijective, 392 blocks
    const int m0  = (swz / 4) * 64;
    const int n0  = (swz % 4) * 64;

    const int mm = tid >> 2;
    const int q  = tid & 3;
    const __bf16* arow = A + (size_t)(m0 + mm) * Kdim + q * 16;
    const __bf16* brow = W + (size_t)(n0 + mm) * Kdim + q * 16;

    const int ks_st  = q >> 1;
    const int sub_st = mm >> 4;
    const int row_st = mm & 15;
    const int c0_st  = (q & 1) * 2;
    const int blk_st = ks_st * 4 + sub_st;
    const int off0 = blk_st * 512 + row_st * 32 + ((c0_st ^ (row_st & 3)) * 8);
    const int off1 = blk_st * 512 + row_st * 32 + (((c0_st + 1) ^ (row_st & 3)) * 8);

    const int w    = tid >> 6;
    const int lane = tid & 63;
    const int fr_row = lane & 15;
    const int fr_c   = lane >> 4;
    const int fr_off = fr_row * 32 + ((fr_c ^ (fr_row & 3)) * 8);

    f32x4 acc[4] = {};

    for (int k0 = 0; k0 < Kdim; k0 += 64) {
        bf16x8 av0 = *(const bf16x8*)(arow + k0);
        bf16x8 av1 = *(const bf16x8*)(arow + k0 + 8);
        bf16x8 bv0 = *(const bf16x8*)(brow + k0);
        bf16x8 bv1 = *(const bf16x8*)(brow + k0 + 8);
        __syncthreads();
        *(bf16x8*)&As[off0] = av0;
        *(bf16x8*)&As[off1] = av1;
        *(bf16x8*)&Bs[off0] = bv0;
        *(bf16x8*)&Bs[off1] = bv1;
        __syncthreads();
        #pragma unroll
        for (int ks = 0; ks < 2; ++ks) {
            bf16x8 af = *(const bf16x8*)&As[(ks * 4 + w) * 512 + fr_off];
            #pragma unroll
            for (int n = 0; n < 4; ++n) {
                bf16x8 bfr = *(const bf16x8*)&Bs[(ks * 4 + n) * 512 + fr_off];
                acc[n] = __builtin_amdgcn_mfma_f32_16x16x32_bf16(af, bfr, acc[n], 0, 0, 0);
            }
        }
    }

    #pragma unroll
    for (int n = 0; n < 4; ++n) {
        const int gcol = n0 + n * 16 + fr_row;
        const float bs_ = bias[gcol];
        #pragma unroll
        for (int r = 0; r < 4; ++r) {
            const int grow = m0 + w * 16 + fr_c * 4 + r;
            Cout[(size_t)grow * N + gcol] = acc[n][r] + bs_;
        }
    }
}

// Neighborhood attention, 8x8 query tile per (b, head). 256 threads.
// Halo = 14x14 = 196 pixels (3.06 halo/query vs 4.38 for 8x4 tile: -30%
// gather loads). K and V staged to SEPARATE LDS regions up front -> 2 barriers.
// Thread map: q = tid>>2 (64 queries), r = tid&3.
// QK: each r-thread covers keys k = r+4*tt; 4-lane shfl reduce.
// PV: thread (q,r) sums all 49 keys for dims [r*8, r*8+8) -> no reduce.
// LDS: 196*40*2B * 2 + 64*49*4B = 43.9 KB -> 3 blocks/CU; grid 784 ~= 3/CU.
__global__ __launch_bounds__(256, 3) void nattn_88(
    const __bf16* __restrict__ qkv, __bf16* __restrict__ attn_out,
    float* __restrict__ attn_glob)
{
    __shared__ __align__(16) __bf16 Ks[196 * 40];
    __shared__ __align__(16) __bf16 Vs[196 * 40];
    __shared__ float Ss[64 * 49];

    const int bid = blockIdx.x;
    const int swz = (bid & 7) * 98 + (bid >> 3);    // bijective, 784 blocks
    const int head = swz & 7;
    int t = swz >> 3;                               // 0..97
    const int tj = t % 7; t /= 7;
    const int ti = t % 7;
    const int b  = t / 7;
    const int tid = threadIdx.x;

    int base_h = ti * 8 - 3; if (base_h < 0) base_h = 0; if (base_h > Hh - 14) base_h = Hh - 14;
    int base_w = tj * 8 - 3; if (base_w < 0) base_w = 0; if (base_w > Ww - 14) base_w = Ww - 14;

    const int pixb = b * HWsz;
    const int hoff = head * 32;

    // --- stage K and V: 196 pixels x 4 chunks of 8 dims each ---
    #pragma unroll
    for (int it = 0; it < 4; ++it) {
        const int idx = tid + it * 256;
        if (idx < 784) {
            const int p = idx >> 2, c = idx & 3;
            const size_t rb = (size_t)(pixb + (base_h + p / 14) * Ww + base_w + p % 14) * 768
                              + hoff + c * 8;
            *(bf16x8*)&Ks[p * 40 + c * 8] = *(const bf16x8*)&qkv[rb + 256];
            *(bf16x8*)&Vs[p * 40 + c * 8] = *(const bf16x8*)&qkv[rb + 512];
        }
    }

    const int q  = tid >> 2;                 // 0..63
    const int r  = tid & 3;                  // 0..3
    const int qi = ti * 8 + (q >> 3);
    const int qj = tj * 8 + (q & 7);

    float qreg[32];
    {
        const __bf16* qp = &qkv[(size_t)(pixb + qi * Ww + qj) * 768 + hoff];
        #pragma unroll
        for (int c = 0; c < 4; ++c) {
            bf16x8 qv = *(const bf16x8*)(qp + c * 8);
            #pragma unroll
            for (int j = 0; j < 8; ++j) qreg[c * 8 + j] = (float)qv[j];
        }
    }
    __syncthreads();

    int ih0 = qi - 3; if (ih0 < 0) ih0 = 0; if (ih0 > Hh - 7) ih0 = Hh - 7;
    int iw0 = qj - 3; if (iw0 < 0) iw0 = 0; if (iw0 > Ww - 7) iw0 = Ww - 7;
    const int lh0 = ih0 - base_h, lw0 = iw0 - base_w;

    // --- QK: keys k = r + 4*tt ---
    float sc[13];
    float mx = -1e30f;
    #pragma unroll
    for (int tt = 0; tt < 13; ++tt) {
        const int k = r + 4 * tt;
        if (k < 49) {
            const __bf16* kp = &Ks[((lh0 + k / 7) * 14 + lw0 + k % 7) * 40];
            float acc = 0.f;
            #pragma unroll
            for (int c = 0; c < 4; ++c) {
                bf16x8 kv = *(const bf16x8*)(kp + c * 8);
                #pragma unroll
                for (int j = 0; j < 8; ++j)
                    acc += qreg[c * 8 + j] * (float)kv[j];
            }
            sc[tt] = acc;
            mx = fmaxf(mx, acc);
        }
    }
    mx = fmaxf(mx, __shfl_xor(mx, 1));
    mx = fmaxf(mx, __shfl_xor(mx, 2));
    float sum = 0.f;
    #pragma unroll
    for (int tt = 0; tt < 13; ++tt) {
        const int k = r + 4 * tt;
        if (k < 49) { sc[tt] = __expf(sc[tt] - mx); sum += sc[tt]; }
    }
    sum += __shfl_xor(sum, 1);
    sum += __shfl_xor(sum, 2);
    const float inv = 1.f / sum;
    #pragma unroll
    for (int tt = 0; tt < 13; ++tt) {
        const int k = r + 4 * tt;
        if (k < 49) Ss[q * 49 + k] = sc[tt] * inv;
    }
    __syncthreads();

    // --- attn probs -> global ---
    const size_t agbase = (size_t)(b * NHh + head) * HWsz;
    for (int idx = tid; idx < 64 * 49; idx += 256) {
        const int qq = idx / 49, k = idx - qq * 49;
        attn_glob[(agbase + (ti * 8 + (qq >> 3)) * Ww + tj * 8 + (qq & 7)) * 49 + k]
            = Ss[qq * 49 + k];
    }

    // --- PV: thread (q, r) accumulates dims [r*8, r*8+8) over all 49 keys ---
    float a[8] = {};
    #pragma unroll
    for (int kh = 0; kh < 7; ++kh) {
        const __bf16* vrow0 = &Vs[((lh0 + kh) * 14 + lw0) * 40 + r * 8];
        const float* ps = &Ss[q * 49 + kh * 7];
        #pragma unroll
        for (int kw = 0; kw < 7; ++kw) {
            const float pr = ps[kw];
            bf16x8 v8 = *(const bf16x8*)(vrow0 + kw * 40);
            #pragma unroll
            for (int j = 0; j < 8; ++j)
                a[j] += pr * (float)v8[j];
        }
    }
    bf16x8 o = { (__bf16)a[0], (__bf16)a[1], (__bf16)a[2], (__bf16)a[3],
                 (__bf16)a[4], (__bf16)a[5], (__bf16)a[6], (__bf16)a[7] };
    *(bf16x8*)(attn_out + (size_t)(pixb + qi * Ww + qj) * 256 + hoff + r * 8) = o;
}

extern "C" void kernel_launch(void* const* d_in, const int* in_sizes, int n_in,
                              void* d_out, int out_size, void* d_ws, size_t ws_size,
                              hipStream_t stream)
{
    const float* x      = (const float*)d_in[0];
    const float* w_qk   = (const float*)d_in[1];
    const float* w_v    = (const float*)d_in[2];
    const float* w_proj = (const float*)d_in[3];
    const float* b_proj = (const float*)d_in[4];

    float* out       = (float*)d_out;                    // chunk 0: (B,H,W,C)
    float* attn_glob = out + (size_t)Mtot * Cc;          // chunk 1: (B,NH,H,W,49)

    __bf16* xb      = (__bf16*)d_ws;                     // M x 256
    __bf16* wallb   = xb + (size_t)Mtot * 256;           // 768 x 256 (qk | v)
    __bf16* wpb     = wallb + 768 * 256;                 // 256 x 256
    __bf16* qkv_ws  = wpb + 256 * 256;                   // M x 768 (q|k|v)
    __bf16* attn_ws = qkv_ws + (size_t)Mtot * 768;       // M x 256

    const float scale = 0.17677669529663687f;            // HD^-0.5

    prep_bf16<<<912, 256, 0, stream>>>(x, w_qk, w_v, w_proj, xb, wallb, wpb);

    gemm_qkv_b<<<1176, 256, 0, stream>>>(xb, wallb, qkv_ws, scale);

    nattn_88<<<784, 256, 0, stream>>>(qkv_ws, attn_ws, attn_glob);

    gemm_proj_b<<<392, 256, 0, stream>>>(attn_ws, wpb, out, b_proj);
}